// Round 9
// baseline (197.154 us; speedup 1.0000x reference)
//
#include <hip/hip_runtime.h>
#include <hip/hip_bf16.h>
#include <stdint.h>

// Problem constants
#define Bc 4
#define Tc 2048
#define Dc 512
#define Hc 8
// DH = 64, 3D = 1536, M = B*T = 8192

typedef __bf16 bf16x8 __attribute__((ext_vector_type(8)));
typedef float  f32x4  __attribute__((ext_vector_type(4)));
typedef float  f32x16 __attribute__((ext_vector_type(16)));
typedef unsigned short u16x8 __attribute__((ext_vector_type(8)));

__device__ __forceinline__ unsigned short f2b(float f) {
  union { float f; unsigned u; } v; v.f = f;
  unsigned r = v.u + 0x7fffu + ((v.u >> 16) & 1u);   // RNE f32->bf16
  return (unsigned short)(r >> 16);
}

__device__ __forceinline__ bf16x8 ld_frag(const unsigned short* p) {
  u16x8 u = *(const u16x8*)p;
  return __builtin_bit_cast(bf16x8, u);
}

__device__ __forceinline__ void gload_lds16(const unsigned short* g, unsigned short* l) {
  __builtin_amdgcn_global_load_lds((const __attribute__((address_space(1))) void*)g,
                                   (__attribute__((address_space(3))) void*)l,
                                   16, 0, 0);
}

__device__ __forceinline__ unsigned cvtpk_bf16(float lo, float hi) {
  unsigned r;
  asm("v_cvt_pk_bf16_f32 %0, %1, %2" : "=v"(r) : "v"(lo), "v"(hi));
  return r;
}

// exchanges upper 32 lanes of a with lower 32 lanes of b
__device__ __forceinline__ void perm32swap(unsigned& a, unsigned& b) {
  asm volatile("v_permlane32_swap_b32 %0, %1" : "+v"(a), "+v"(b));
}

// ---------------- f32 -> bf16 convert (vectorized) ----------------
__global__ __launch_bounds__(256) void cvt_bf16(const float* __restrict__ in,
                                                unsigned short* __restrict__ out, int n) {
  int i = (blockIdx.x * 256 + threadIdx.x) * 8;
  if (i >= n) return;
  float4 a = *(const float4*)&in[i];
  float4 b = *(const float4*)&in[i + 4];
  u16x8 r;
  r[0] = f2b(a.x); r[1] = f2b(a.y); r[2] = f2b(a.z); r[3] = f2b(a.w);
  r[4] = f2b(b.x); r[5] = f2b(b.y); r[6] = f2b(b.z); r[7] = f2b(b.w);
  *(u16x8*)&out[i] = r;
}

// ---------------- mask -> additive f32 row ----------------
__global__ __launch_bounds__(256) void mask_f32(const int* __restrict__ amask,
                                                float* __restrict__ maddv, int n) {
  int i = blockIdx.x * 256 + threadIdx.x;
  if (i < n) maddv[i] = amask[i] ? 0.f : -1e30f;
}

// ---------------- f32 [R][C] -> bf16 [C][R] tiled transpose ----------------
__global__ __launch_bounds__(256) void transp_bf16(const float* __restrict__ in,
                                                   unsigned short* __restrict__ out,
                                                   int R, int C) {
  __shared__ float tile[32][33];
  int c0 = blockIdx.x * 32, r0 = blockIdx.y * 32;
  int lx = threadIdx.x & 31, ly = threadIdx.x >> 5;   // 32 x 8
  #pragma unroll
  for (int i = 0; i < 32; i += 8) tile[ly + i][lx] = in[(size_t)(r0 + ly + i) * C + c0 + lx];
  __syncthreads();
  #pragma unroll
  for (int i = 0; i < 32; i += 8) out[(size_t)(c0 + ly + i) * R + r0 + lx] = f2b(tile[lx][ly + i]);
}

// ---------------- bf16 V pre-transpose: qkv V-part -> vtg[(b*512+dg)][T] ----------------
__global__ __launch_bounds__(256) void transp_v(const unsigned short* __restrict__ qkv,
                                                unsigned short* __restrict__ vtg) {
  __shared__ unsigned short tile[32][34];
  int t0 = blockIdx.x * 32;          // 64
  int d0 = blockIdx.y * 32;          // 16
  int b  = blockIdx.z;               // 4
  int lx = threadIdx.x & 31, ly = threadIdx.x >> 5;   // 32 x 8
  #pragma unroll
  for (int i = 0; i < 32; i += 8)
    tile[ly + i][lx] = qkv[(size_t)(b * Tc + t0 + ly + i) * 1536 + 1024 + d0 + lx];
  __syncthreads();
  #pragma unroll
  for (int i = 0; i < 32; i += 8)
    vtg[(size_t)(b * 512 + d0 + ly + i) * Tc + t0 + lx] = tile[lx][ly + i];
}

// ---------------- bf16 GEMM: C[M,N] = A[M,K] * Bt[N,K]^T ----------------
template <int N, int OUTF32>
__global__ __launch_bounds__(256) void gemm_bt(const unsigned short* __restrict__ A,
                                               const unsigned short* __restrict__ Bt,
                                               void* __restrict__ Cout, int M, int K) {
  __shared__ unsigned short As[128 * 32];
  __shared__ unsigned short Bs[128 * 32];
  const int tid = threadIdx.x;
  const int lane = tid & 63;
  const int wid = tid >> 6;
  const int wm = (wid >> 1) * 64;
  const int wn = (wid & 1) * 64;
  const int m0 = blockIdx.x * 128;
  const int n0 = blockIdx.y * 128;
  const int l15 = lane & 15;
  const int lg = lane >> 4;

  f32x4 acc[4][4];
  #pragma unroll
  for (int i = 0; i < 4; i++)
    #pragma unroll
    for (int j = 0; j < 4; j++) acc[i][j] = (f32x4){0.f, 0.f, 0.f, 0.f};

  const int srow = tid >> 2;
  const int scol = (tid & 3) * 8;

  for (int k0 = 0; k0 < K; k0 += 32) {
    __syncthreads();
    gload_lds16(&A[(size_t)(m0 + srow) * K + k0 + scol],      &As[tid * 8]);
    gload_lds16(&A[(size_t)(m0 + 64 + srow) * K + k0 + scol], &As[2048 + tid * 8]);
    gload_lds16(&Bt[(size_t)(n0 + srow) * K + k0 + scol],      &Bs[tid * 8]);
    gload_lds16(&Bt[(size_t)(n0 + 64 + srow) * K + k0 + scol], &Bs[2048 + tid * 8]);
    __syncthreads();
    bf16x8 af[4], bfr[4];
    #pragma unroll
    for (int m = 0; m < 4; m++) af[m] = ld_frag(&As[(wm + m * 16 + l15) * 32 + lg * 8]);
    #pragma unroll
    for (int n = 0; n < 4; n++) bfr[n] = ld_frag(&Bs[(wn + n * 16 + l15) * 32 + lg * 8]);
    #pragma unroll
    for (int m = 0; m < 4; m++)
      #pragma unroll
      for (int n = 0; n < 4; n++)
        acc[m][n] = __builtin_amdgcn_mfma_f32_16x16x32_bf16(af[m], bfr[n], acc[m][n], 0, 0, 0);
  }

  #pragma unroll
  for (int m = 0; m < 4; m++)
    #pragma unroll
    for (int n = 0; n < 4; n++)
      #pragma unroll
      for (int j = 0; j < 4; j++) {
        int row = m0 + wm + m * 16 + lg * 4 + j;
        int col = n0 + wn + n * 16 + l15;
        float v = acc[m][n][j];
        if (OUTF32) ((float*)Cout)[(size_t)row * N + col] = v;
        else ((unsigned short*)Cout)[(size_t)row * N + col] = f2b(v);
      }
}

// ---------------- fused attention (8 waves x 32 q, 32x32 MFMA, in-register P) ----------------
// Block: 512 thr = 8 waves, QBLK=256 (32 q-rows/wave), grid 256 = 1 block/CU.
// KBLK=64, single-buffered 2-barrier staging (R2-proven): barrier -> stage-issue
// (2 gload_lds/thread) -> bias+maddv prefetch -> barrier(vmcnt drain) -> compute.
// Swapped QK^T (mfma32(K,Q)): lane holds S^T[32 keys][q=lane&31]; P packed
// in-register via v_cvt_pk_bf16_f32 + v_permlane32_swap_b32 (R6-refcheck'd math)
// -> PV A-frags with NO LDS round-trip. K/V chunk-XOR c^(row&7) (R2-proven form).
__global__ __launch_bounds__(512) void attn_kernel(const unsigned short* __restrict__ qkv,
                                                   const unsigned short* __restrict__ vtg,
                                                   const float* __restrict__ bias,
                                                   const float* __restrict__ maddv,
                                                   unsigned short* __restrict__ ctx) {
  __shared__ unsigned short Ks[64 * 64];
  __shared__ unsigned short Vs[64 * 64];   // Vs[d][key], chunk-swizzled

  const int bid = blockIdx.x;
  const int b = bid >> 6;                  // /(Hc * Tc/256) = /64
  const int h = (bid >> 3) & 7;
  const int q0 = (bid & 7) * 256;
  const int tid = threadIdx.x;
  const int lane = tid & 63;
  const int w = tid >> 6;                  // 0..7
  const int l31 = lane & 31;
  const int hi = lane >> 5;
  const int swz = l31 & 7;

  const float LOG2E = 1.44269504f;
  const float SC = 0.125f * LOG2E;

  // Q fragments (B operand): q-col = l31, k-elems d = s*16 + hi*8 + e  [R6-verified]
  const int qrow = q0 + w * 32 + l31;
  const size_t qoff = (size_t)(b * Tc + qrow) * 1536 + h * 64;
  bf16x8 qf0 = ld_frag(&qkv[qoff + 0 * 16 + hi * 8]);
  bf16x8 qf1 = ld_frag(&qkv[qoff + 1 * 16 + hi * 8]);
  bf16x8 qf2 = ld_frag(&qkv[qoff + 2 * 16 + hi * 8]);
  bf16x8 qf3 = ld_frag(&qkv[qoff + 3 * 16 + hi * 8]);

  u16x8 ou;
  #pragma unroll
  for (int e = 0; e < 8; e++) ou[e] = 0x3f80;   // bf16 1.0
  const bf16x8 ones = __builtin_bit_cast(bf16x8, ou);

  f32x16 o0, o1, osum;
  #pragma unroll
  for (int i = 0; i < 16; i++) { o0[i] = 0.f; o1[i] = 0.f; osum[i] = 0.f; }

  // staging: thread t -> LDS row sr = t>>3 (0..63), chunk c = t&7; src chunk c^(sr&7)
  const int sr = tid >> 3;
  const int sgc = (tid & 7) ^ (sr & 7);
  const size_t kcol = (size_t)(b * Tc) * 1536 + 512 + h * 64;
  const unsigned short* vrow = &vtg[(size_t)(b * 512 + h * 64) * Tc];

  // bias row fixed per lane (q = qrow); maddv pre-folded mask
  const float* bq = bias + (size_t)(b * Tc + qrow) * Tc;
  const float* mf = maddv + b * Tc;

  for (int kt = 0; kt < Tc; kt += 64) {
    __syncthreads();                       // previous compute done
    // ---- stage K[key][d] and V[d][key] tiles (one gload_lds each) ----
    {
      const size_t kbase = kcol + (size_t)kt * 1536;
      gload_lds16(&qkv[kbase + (size_t)sr * 1536 + sgc * 8], &Ks[tid * 8]);
      gload_lds16(&vrow[(size_t)sr * Tc + kt + sgc * 8],     &Vs[tid * 8]);
    }
    // ---- bias + maddv prefetch (fills the stage window) ----
    // reg r of kt2-tile: key = kt + kt2*32 + (r&3) + 8*(r>>2) + 4*hi
    float4 bf_[8];
    #pragma unroll
    for (int g2 = 0; g2 < 8; g2++) {
      const int idx = kt + g2 * 8 + hi * 4;
      float4 bb = *(const float4*)&bq[idx];
      float4 mm = *(const float4*)&mf[idx];
      bf_[g2].x = fmaf(bb.x, LOG2E, mm.x);
      bf_[g2].y = fmaf(bb.y, LOG2E, mm.y);
      bf_[g2].z = fmaf(bb.z, LOG2E, mm.z);
      bf_[g2].w = fmaf(bb.w, LOG2E, mm.w);
    }
    __syncthreads();                       // implicit vmcnt(0): tiles ready

    #pragma unroll
    for (int kt2 = 0; kt2 < 2; kt2++) {
      // ---- QK^T: S^T[key][q], 32 keys, DH=64 as 4 k16-steps ----
      const unsigned short* krow_ = &Ks[(kt2 * 32 + l31) * 64];
      bf16x8 ka0 = ld_frag(&krow_[((0 + hi) ^ swz) * 8]);
      bf16x8 ka1 = ld_frag(&krow_[((2 + hi) ^ swz) * 8]);
      bf16x8 ka2 = ld_frag(&krow_[((4 + hi) ^ swz) * 8]);
      bf16x8 ka3 = ld_frag(&krow_[((6 + hi) ^ swz) * 8]);
      f32x16 s_;
      #pragma unroll
      for (int i = 0; i < 16; i++) s_[i] = 0.f;
      __builtin_amdgcn_s_setprio(1);
      s_ = __builtin_amdgcn_mfma_f32_32x32x16_bf16(ka0, qf0, s_, 0, 0, 0);
      s_ = __builtin_amdgcn_mfma_f32_32x32x16_bf16(ka1, qf1, s_, 0, 0, 0);
      s_ = __builtin_amdgcn_mfma_f32_32x32x16_bf16(ka2, qf2, s_, 0, 0, 0);
      s_ = __builtin_amdgcn_mfma_f32_32x32x16_bf16(ka3, qf3, s_, 0, 0, 0);
      __builtin_amdgcn_s_setprio(0);

      // ---- p = exp2(s*SC + bias*log2e + mask) ----
      float p[16];
      #pragma unroll
      for (int r = 0; r < 16; r++) {
        const float bb = ((const float*)&bf_[kt2 * 4 + (r >> 2)])[r & 3];
        p[r] = exp2f(fmaf(s_[r], SC, bb));
      }

      // ---- pack to PV A-frags: 8 cvt_pk + 4 permlane32_swap [R6-verified] ----
      unsigned pk0 = cvtpk_bf16(p[0], p[1]);
      unsigned pk1 = cvtpk_bf16(p[2], p[3]);
      unsigned pk2 = cvtpk_bf16(p[4], p[5]);
      unsigned pk3 = cvtpk_bf16(p[6], p[7]);
      unsigned pk4 = cvtpk_bf16(p[8], p[9]);
      unsigned pk5 = cvtpk_bf16(p[10], p[11]);
      unsigned pk6 = cvtpk_bf16(p[12], p[13]);
      unsigned pk7 = cvtpk_bf16(p[14], p[15]);
      perm32swap(pk0, pk2);
      perm32swap(pk1, pk3);
      perm32swap(pk4, pk6);
      perm32swap(pk5, pk7);
      uint4 pa0u = {pk0, pk1, pk2, pk3};   // keys kt2*32 + 0..15
      uint4 pa1u = {pk4, pk5, pk6, pk7};   // keys kt2*32 + 16..31
      bf16x8 pa0 = __builtin_bit_cast(bf16x8, pa0u);
      bf16x8 pa1 = __builtin_bit_cast(bf16x8, pa1u);

      // ---- PV + row-sum: V-frag chunk = kt2*4 + s*2 + hi  [R6-verified] ----
      bf16x8 vb00 = ld_frag(&Vs[(l31) * 64      + ((kt2 * 4 + 0 + hi) ^ swz) * 8]);
      bf16x8 vb01 = ld_frag(&Vs[(32 + l31) * 64 + ((kt2 * 4 + 0 + hi) ^ swz) * 8]);
      bf16x8 vb10 = ld_frag(&Vs[(l31) * 64      + ((kt2 * 4 + 2 + hi) ^ swz) * 8]);
      bf16x8 vb11 = ld_frag(&Vs[(32 + l31) * 64 + ((kt2 * 4 + 2 + hi) ^ swz) * 8]);
      __builtin_amdgcn_s_setprio(1);
      osum = __builtin_amdgcn_mfma_f32_32x32x16_bf16(pa0, ones, osum, 0, 0, 0);
      osum = __builtin_amdgcn_mfma_f32_32x32x16_bf16(pa1, ones, osum, 0, 0, 0);
      o0 = __builtin_amdgcn_mfma_f32_32x32x16_bf16(pa0, vb00, o0, 0, 0, 0);
      o1 = __builtin_amdgcn_mfma_f32_32x32x16_bf16(pa0, vb01, o1, 0, 0, 0);
      o0 = __builtin_amdgcn_mfma_f32_32x32x16_bf16(pa1, vb10, o0, 0, 0, 0);
      o1 = __builtin_amdgcn_mfma_f32_32x32x16_bf16(pa1, vb11, o1, 0, 0, 0);
      __builtin_amdgcn_s_setprio(0);
    }
  }

  // epilogue [R6-verified]: q = q0 + w*32 + (r&3)+8*(r>>2)+4*hi; d = l31 (+32 for o1)
  #pragma unroll
  for (int r = 0; r < 16; r++) {
    const int qr = q0 + w * 32 + (r & 3) + 8 * (r >> 2) + 4 * hi;
    const float inv = 1.0f / osum[r];
    const size_t base = (size_t)(b * Tc + qr) * Dc + h * 64;
    ctx[base + l31]      = f2b(o0[r] * inv);
    ctx[base + 32 + l31] = f2b(o1[r] * inv);
  }
}

// ---------------- launcher ----------------
extern "C" void kernel_launch(void* const* d_in, const int* in_sizes, int n_in,
                              void* d_out, int out_size, void* d_ws, size_t ws_size,
                              hipStream_t stream) {
  const float* x     = (const float*)d_in[0];
  const int*   amask = (const int*)d_in[1];
  const float* bias  = (const float*)d_in[2];
  const float* Wqkv  = (const float*)d_in[3];
  const float* Wout  = (const float*)d_in[4];
  float* out = (float*)d_out;
  char* ws = (char*)d_ws;

  // ws layout (bytes): xb 8,388,608 | wqkvT 1,572,864 | woutT 524,288 |
  //   qkv 25,165,824 | ctx 8,388,608 | vtg 8,388,608 | maddv 32,768  (~52.5 MB)
  unsigned short* xb    = (unsigned short*)(ws + 0);
  unsigned short* wqkvT = (unsigned short*)(ws + 8388608);
  unsigned short* woutT = (unsigned short*)(ws + 9961472);
  unsigned short* qkv   = (unsigned short*)(ws + 10485760);
  unsigned short* ctx   = (unsigned short*)(ws + 35651584);
  unsigned short* vtg   = (unsigned short*)(ws + 44040192);
  float*          maddv = (float*)(ws + 52428800);

  cvt_bf16<<<2048, 256, 0, stream>>>(x, xb, Bc * Tc * Dc);
  mask_f32<<<32, 256, 0, stream>>>(amask, maddv, Bc * Tc);
  transp_bf16<<<dim3(48, 16), 256, 0, stream>>>(Wqkv, wqkvT, 512, 1536);
  transp_bf16<<<dim3(16, 16), 256, 0, stream>>>(Wout, woutT, 512, 512);
  gemm_bt<1536, 0><<<dim3(64, 12), 256, 0, stream>>>(xb, wqkvT, (void*)qkv, 8192, 512);
  transp_v<<<dim3(64, 16, 4), 256, 0, stream>>>(qkv, vtg);
  attn_kernel<<<256, 512, 0, stream>>>(qkv, vtg, bias, maddv, ctx);
  gemm_bt<512, 1><<<dim3(64, 4), 256, 0, stream>>>(ctx, woutT, (void*)out, 8192, 512);
}

// Round 10
// 154.278 us; speedup vs baseline: 1.2779x; 1.2779x over previous
//
#include <hip/hip_runtime.h>
#include <hip/hip_bf16.h>
#include <stdint.h>

// Problem constants
#define Bc 4
#define Tc 2048
#define Dc 512
#define Hc 8
// DH = 64, 3D = 1536, M = B*T = 8192

typedef __bf16 bf16x8 __attribute__((ext_vector_type(8)));
typedef float  f32x4  __attribute__((ext_vector_type(4)));
typedef float  f32x16 __attribute__((ext_vector_type(16)));
typedef unsigned short u16x8 __attribute__((ext_vector_type(8)));

__device__ __forceinline__ unsigned short f2b(float f) {
  union { float f; unsigned u; } v; v.f = f;
  unsigned r = v.u + 0x7fffu + ((v.u >> 16) & 1u);   // RNE f32->bf16
  return (unsigned short)(r >> 16);
}

__device__ __forceinline__ bf16x8 ld_frag(const unsigned short* p) {
  u16x8 u = *(const u16x8*)p;
  return __builtin_bit_cast(bf16x8, u);
}

__device__ __forceinline__ void gload_lds16(const unsigned short* g, unsigned short* l) {
  __builtin_amdgcn_global_load_lds((const __attribute__((address_space(1))) void*)g,
                                   (__attribute__((address_space(3))) void*)l,
                                   16, 0, 0);
}

__device__ __forceinline__ unsigned cvtpk_bf16(float lo, float hi) {
  unsigned r;
  asm("v_cvt_pk_bf16_f32 %0, %1, %2" : "=v"(r) : "v"(lo), "v"(hi));
  return r;
}

// exchanges upper 32 lanes of a with lower 32 lanes of b
__device__ __forceinline__ void perm32swap(unsigned& a, unsigned& b) {
  asm volatile("v_permlane32_swap_b32 %0, %1" : "+v"(a), "+v"(b));
}

// ---------------- f32 -> bf16 convert (vectorized) ----------------
__global__ __launch_bounds__(256) void cvt_bf16(const float* __restrict__ in,
                                                unsigned short* __restrict__ out, int n) {
  int i = (blockIdx.x * 256 + threadIdx.x) * 8;
  if (i >= n) return;
  float4 a = *(const float4*)&in[i];
  float4 b = *(const float4*)&in[i + 4];
  u16x8 r;
  r[0] = f2b(a.x); r[1] = f2b(a.y); r[2] = f2b(a.z); r[3] = f2b(a.w);
  r[4] = f2b(b.x); r[5] = f2b(b.y); r[6] = f2b(b.z); r[7] = f2b(b.w);
  *(u16x8*)&out[i] = r;
}

// ---------------- mask -> additive f32 row ----------------
__global__ __launch_bounds__(256) void mask_f32(const int* __restrict__ amask,
                                                float* __restrict__ maddv, int n) {
  int i = blockIdx.x * 256 + threadIdx.x;
  if (i < n) maddv[i] = amask[i] ? 0.f : -1e30f;
}

// ---------------- f32 [R][C] -> bf16 [C][R] tiled transpose ----------------
__global__ __launch_bounds__(256) void transp_bf16(const float* __restrict__ in,
                                                   unsigned short* __restrict__ out,
                                                   int R, int C) {
  __shared__ float tile[32][33];
  int c0 = blockIdx.x * 32, r0 = blockIdx.y * 32;
  int lx = threadIdx.x & 31, ly = threadIdx.x >> 5;   // 32 x 8
  #pragma unroll
  for (int i = 0; i < 32; i += 8) tile[ly + i][lx] = in[(size_t)(r0 + ly + i) * C + c0 + lx];
  __syncthreads();
  #pragma unroll
  for (int i = 0; i < 32; i += 8) out[(size_t)(c0 + ly + i) * R + r0 + lx] = f2b(tile[lx][ly + i]);
}

// ---------------- bf16 V pre-transpose: qkv V-part -> vtg[(b*512+dg)][T] ----------------
__global__ __launch_bounds__(256) void transp_v(const unsigned short* __restrict__ qkv,
                                                unsigned short* __restrict__ vtg) {
  __shared__ unsigned short tile[32][34];
  int t0 = blockIdx.x * 32;          // 64
  int d0 = blockIdx.y * 32;          // 16
  int b  = blockIdx.z;               // 4
  int lx = threadIdx.x & 31, ly = threadIdx.x >> 5;   // 32 x 8
  #pragma unroll
  for (int i = 0; i < 32; i += 8)
    tile[ly + i][lx] = qkv[(size_t)(b * Tc + t0 + ly + i) * 1536 + 1024 + d0 + lx];
  __syncthreads();
  #pragma unroll
  for (int i = 0; i < 32; i += 8)
    vtg[(size_t)(b * 512 + d0 + ly + i) * Tc + t0 + lx] = tile[lx][ly + i];
}

// ---------------- bf16 GEMM: C[M,N] = A[M,K] * Bt[N,K]^T ----------------
template <int N, int OUTF32>
__global__ __launch_bounds__(256) void gemm_bt(const unsigned short* __restrict__ A,
                                               const unsigned short* __restrict__ Bt,
                                               void* __restrict__ Cout, int M, int K) {
  __shared__ unsigned short As[128 * 32];
  __shared__ unsigned short Bs[128 * 32];
  const int tid = threadIdx.x;
  const int lane = tid & 63;
  const int wid = tid >> 6;
  const int wm = (wid >> 1) * 64;
  const int wn = (wid & 1) * 64;
  const int m0 = blockIdx.x * 128;
  const int n0 = blockIdx.y * 128;
  const int l15 = lane & 15;
  const int lg = lane >> 4;

  f32x4 acc[4][4];
  #pragma unroll
  for (int i = 0; i < 4; i++)
    #pragma unroll
    for (int j = 0; j < 4; j++) acc[i][j] = (f32x4){0.f, 0.f, 0.f, 0.f};

  const int srow = tid >> 2;
  const int scol = (tid & 3) * 8;

  for (int k0 = 0; k0 < K; k0 += 32) {
    __syncthreads();
    gload_lds16(&A[(size_t)(m0 + srow) * K + k0 + scol],      &As[tid * 8]);
    gload_lds16(&A[(size_t)(m0 + 64 + srow) * K + k0 + scol], &As[2048 + tid * 8]);
    gload_lds16(&Bt[(size_t)(n0 + srow) * K + k0 + scol],      &Bs[tid * 8]);
    gload_lds16(&Bt[(size_t)(n0 + 64 + srow) * K + k0 + scol], &Bs[2048 + tid * 8]);
    __syncthreads();
    bf16x8 af[4], bfr[4];
    #pragma unroll
    for (int m = 0; m < 4; m++) af[m] = ld_frag(&As[(wm + m * 16 + l15) * 32 + lg * 8]);
    #pragma unroll
    for (int n = 0; n < 4; n++) bfr[n] = ld_frag(&Bs[(wn + n * 16 + l15) * 32 + lg * 8]);
    #pragma unroll
    for (int m = 0; m < 4; m++)
      #pragma unroll
      for (int n = 0; n < 4; n++)
        acc[m][n] = __builtin_amdgcn_mfma_f32_16x16x32_bf16(af[m], bfr[n], acc[m][n], 0, 0, 0);
  }

  #pragma unroll
  for (int m = 0; m < 4; m++)
    #pragma unroll
    for (int n = 0; n < 4; n++)
      #pragma unroll
      for (int j = 0; j < 4; j++) {
        int row = m0 + wm + m * 16 + lg * 4 + j;
        int col = n0 + wn + n * 16 + l15;
        float v = acc[m][n][j];
        if (OUTF32) ((float*)Cout)[(size_t)row * N + col] = v;
        else ((unsigned short*)Cout)[(size_t)row * N + col] = f2b(v);
      }
}

// ---------------- fused attention (4 waves x 32 q, 32x32 MFMA, in-register P) ----------------
// Block: 256 thr = 4 waves, QBLK=128 (32 q-rows/wave), grid 512 = 2 blocks/CU
// (R9's compute core verbatim — refcheck'd in R6+R9 — with residency fixed:
// two independent blocks per CU so barrier drains overlap the other block's
// compute, the mechanism that made R2's 123us work).
// KBLK=64, single-buffered 2-barrier staging; K/V chunk-XOR c^(row&7).
// Swapped QK^T (mfma32(K,Q)); P packed in-register (cvt_pk + permlane32_swap).
__global__ __launch_bounds__(256) void attn_kernel(const unsigned short* __restrict__ qkv,
                                                   const unsigned short* __restrict__ vtg,
                                                   const float* __restrict__ bias,
                                                   const float* __restrict__ maddv,
                                                   unsigned short* __restrict__ ctx) {
  __shared__ unsigned short Ks[64 * 64];
  __shared__ unsigned short Vs[64 * 64];   // Vs[d][key], chunk-swizzled

  const int bid = blockIdx.x;
  const int b = bid >> 7;                  // /(Hc * Tc/128) = /128
  const int h = (bid >> 4) & 7;
  const int q0 = (bid & 15) * 128;
  const int tid = threadIdx.x;
  const int lane = tid & 63;
  const int w = tid >> 6;                  // 0..3
  const int l31 = lane & 31;
  const int hi = lane >> 5;
  const int swz = l31 & 7;

  const float LOG2E = 1.44269504f;
  const float SC = 0.125f * LOG2E;

  // Q fragments (B operand): q-col = l31, k-elems d = s*16 + hi*8 + e  [R6/R9-verified]
  const int qrow = q0 + w * 32 + l31;
  const size_t qoff = (size_t)(b * Tc + qrow) * 1536 + h * 64;
  bf16x8 qf0 = ld_frag(&qkv[qoff + 0 * 16 + hi * 8]);
  bf16x8 qf1 = ld_frag(&qkv[qoff + 1 * 16 + hi * 8]);
  bf16x8 qf2 = ld_frag(&qkv[qoff + 2 * 16 + hi * 8]);
  bf16x8 qf3 = ld_frag(&qkv[qoff + 3 * 16 + hi * 8]);

  u16x8 ou;
  #pragma unroll
  for (int e = 0; e < 8; e++) ou[e] = 0x3f80;   // bf16 1.0
  const bf16x8 ones = __builtin_bit_cast(bf16x8, ou);

  f32x16 o0, o1, osum;
  #pragma unroll
  for (int i = 0; i < 16; i++) { o0[i] = 0.f; o1[i] = 0.f; osum[i] = 0.f; }

  // staging: thread t covers LDS rows sr and sr+32 (sr = t>>3), chunk c = t&7;
  // source chunk c^(sr&7) (== c^((sr+32)&7)) — R2-proven pattern
  const int sr = tid >> 3;
  const int sgc = (tid & 7) ^ (sr & 7);
  const size_t kcol = (size_t)(b * Tc) * 1536 + 512 + h * 64;
  const unsigned short* vrow = &vtg[(size_t)(b * 512 + h * 64) * Tc];

  // bias row fixed per lane (q = qrow); maddv pre-folded mask
  const float* bq = bias + (size_t)(b * Tc + qrow) * Tc;
  const float* mf = maddv + b * Tc;

  for (int kt = 0; kt < Tc; kt += 64) {
    __syncthreads();                       // previous compute done
    // ---- stage K[key][d] and V[d][key] tiles (rows sr, sr+32) ----
    {
      const size_t kbase = kcol + (size_t)kt * 1536;
      gload_lds16(&qkv[kbase + (size_t)sr * 1536 + sgc * 8],        &Ks[tid * 8]);
      gload_lds16(&qkv[kbase + (size_t)(sr + 32) * 1536 + sgc * 8], &Ks[2048 + tid * 8]);
      gload_lds16(&vrow[(size_t)sr * Tc + kt + sgc * 8],            &Vs[tid * 8]);
      gload_lds16(&vrow[(size_t)(sr + 32) * Tc + kt + sgc * 8],     &Vs[2048 + tid * 8]);
    }
    // ---- bias + maddv prefetch (fills the stage window) ----
    // reg r of kt2-tile: key = kt + kt2*32 + (r&3) + 8*(r>>2) + 4*hi
    float4 bf_[8];
    #pragma unroll
    for (int g2 = 0; g2 < 8; g2++) {
      const int idx = kt + g2 * 8 + hi * 4;
      float4 bb = *(const float4*)&bq[idx];
      float4 mm = *(const float4*)&mf[idx];
      bf_[g2].x = fmaf(bb.x, LOG2E, mm.x);
      bf_[g2].y = fmaf(bb.y, LOG2E, mm.y);
      bf_[g2].z = fmaf(bb.z, LOG2E, mm.z);
      bf_[g2].w = fmaf(bb.w, LOG2E, mm.w);
    }
    __syncthreads();                       // implicit vmcnt(0): tiles ready

    #pragma unroll
    for (int kt2 = 0; kt2 < 2; kt2++) {
      // ---- QK^T: S^T[key][q], 32 keys, DH=64 as 4 k16-steps ----
      const unsigned short* krow_ = &Ks[(kt2 * 32 + l31) * 64];
      bf16x8 ka0 = ld_frag(&krow_[((0 + hi) ^ swz) * 8]);
      bf16x8 ka1 = ld_frag(&krow_[((2 + hi) ^ swz) * 8]);
      bf16x8 ka2 = ld_frag(&krow_[((4 + hi) ^ swz) * 8]);
      bf16x8 ka3 = ld_frag(&krow_[((6 + hi) ^ swz) * 8]);
      f32x16 s_;
      #pragma unroll
      for (int i = 0; i < 16; i++) s_[i] = 0.f;
      __builtin_amdgcn_s_setprio(1);
      s_ = __builtin_amdgcn_mfma_f32_32x32x16_bf16(ka0, qf0, s_, 0, 0, 0);
      s_ = __builtin_amdgcn_mfma_f32_32x32x16_bf16(ka1, qf1, s_, 0, 0, 0);
      s_ = __builtin_amdgcn_mfma_f32_32x32x16_bf16(ka2, qf2, s_, 0, 0, 0);
      s_ = __builtin_amdgcn_mfma_f32_32x32x16_bf16(ka3, qf3, s_, 0, 0, 0);
      __builtin_amdgcn_s_setprio(0);

      // ---- p = exp2(s*SC + bias*log2e + mask) ----
      float p[16];
      #pragma unroll
      for (int r = 0; r < 16; r++) {
        const float bb = ((const float*)&bf_[kt2 * 4 + (r >> 2)])[r & 3];
        p[r] = exp2f(fmaf(s_[r], SC, bb));
      }

      // ---- pack to PV A-frags: 8 cvt_pk + 4 permlane32_swap [R6/R9-verified] ----
      unsigned pk0 = cvtpk_bf16(p[0], p[1]);
      unsigned pk1 = cvtpk_bf16(p[2], p[3]);
      unsigned pk2 = cvtpk_bf16(p[4], p[5]);
      unsigned pk3 = cvtpk_bf16(p[6], p[7]);
      unsigned pk4 = cvtpk_bf16(p[8], p[9]);
      unsigned pk5 = cvtpk_bf16(p[10], p[11]);
      unsigned pk6 = cvtpk_bf16(p[12], p[13]);
      unsigned pk7 = cvtpk_bf16(p[14], p[15]);
      perm32swap(pk0, pk2);
      perm32swap(pk1, pk3);
      perm32swap(pk4, pk6);
      perm32swap(pk5, pk7);
      uint4 pa0u = {pk0, pk1, pk2, pk3};   // keys kt2*32 + 0..15
      uint4 pa1u = {pk4, pk5, pk6, pk7};   // keys kt2*32 + 16..31
      bf16x8 pa0 = __builtin_bit_cast(bf16x8, pa0u);
      bf16x8 pa1 = __builtin_bit_cast(bf16x8, pa1u);

      // ---- PV + row-sum: V-frag chunk = kt2*4 + s*2 + hi  [R6/R9-verified] ----
      bf16x8 vb00 = ld_frag(&Vs[(l31) * 64      + ((kt2 * 4 + 0 + hi) ^ swz) * 8]);
      bf16x8 vb01 = ld_frag(&Vs[(32 + l31) * 64 + ((kt2 * 4 + 0 + hi) ^ swz) * 8]);
      bf16x8 vb10 = ld_frag(&Vs[(l31) * 64      + ((kt2 * 4 + 2 + hi) ^ swz) * 8]);
      bf16x8 vb11 = ld_frag(&Vs[(32 + l31) * 64 + ((kt2 * 4 + 2 + hi) ^ swz) * 8]);
      __builtin_amdgcn_s_setprio(1);
      osum = __builtin_amdgcn_mfma_f32_32x32x16_bf16(pa0, ones, osum, 0, 0, 0);
      osum = __builtin_amdgcn_mfma_f32_32x32x16_bf16(pa1, ones, osum, 0, 0, 0);
      o0 = __builtin_amdgcn_mfma_f32_32x32x16_bf16(pa0, vb00, o0, 0, 0, 0);
      o1 = __builtin_amdgcn_mfma_f32_32x32x16_bf16(pa0, vb01, o1, 0, 0, 0);
      o0 = __builtin_amdgcn_mfma_f32_32x32x16_bf16(pa1, vb10, o0, 0, 0, 0);
      o1 = __builtin_amdgcn_mfma_f32_32x32x16_bf16(pa1, vb11, o1, 0, 0, 0);
      __builtin_amdgcn_s_setprio(0);
    }
  }

  // epilogue [R6/R9-verified]: q = q0 + w*32 + (r&3)+8*(r>>2)+4*hi; d = l31 (+32 for o1)
  #pragma unroll
  for (int r = 0; r < 16; r++) {
    const int qr = q0 + w * 32 + (r & 3) + 8 * (r >> 2) + 4 * hi;
    const float inv = 1.0f / osum[r];
    const size_t base = (size_t)(b * Tc + qr) * Dc + h * 64;
    ctx[base + l31]      = f2b(o0[r] * inv);
    ctx[base + 32 + l31] = f2b(o1[r] * inv);
  }
}

// ---------------- launcher ----------------
extern "C" void kernel_launch(void* const* d_in, const int* in_sizes, int n_in,
                              void* d_out, int out_size, void* d_ws, size_t ws_size,
                              hipStream_t stream) {
  const float* x     = (const float*)d_in[0];
  const int*   amask = (const int*)d_in[1];
  const float* bias  = (const float*)d_in[2];
  const float* Wqkv  = (const float*)d_in[3];
  const float* Wout  = (const float*)d_in[4];
  float* out = (float*)d_out;
  char* ws = (char*)d_ws;

  // ws layout (bytes): xb 8,388,608 | wqkvT 1,572,864 | woutT 524,288 |
  //   qkv 25,165,824 | ctx 8,388,608 | vtg 8,388,608 | maddv 32,768  (~52.5 MB)
  unsigned short* xb    = (unsigned short*)(ws + 0);
  unsigned short* wqkvT = (unsigned short*)(ws + 8388608);
  unsigned short* woutT = (unsigned short*)(ws + 9961472);
  unsigned short* qkv   = (unsigned short*)(ws + 10485760);
  unsigned short* ctx   = (unsigned short*)(ws + 35651584);
  unsigned short* vtg   = (unsigned short*)(ws + 44040192);
  float*          maddv = (float*)(ws + 52428800);

  cvt_bf16<<<2048, 256, 0, stream>>>(x, xb, Bc * Tc * Dc);
  mask_f32<<<32, 256, 0, stream>>>(amask, maddv, Bc * Tc);
  transp_bf16<<<dim3(48, 16), 256, 0, stream>>>(Wqkv, wqkvT, 512, 1536);
  transp_bf16<<<dim3(16, 16), 256, 0, stream>>>(Wout, woutT, 512, 512);
  gemm_bt<1536, 0><<<dim3(64, 12), 256, 0, stream>>>(xb, wqkvT, (void*)qkv, 8192, 512);
  transp_v<<<dim3(64, 16, 4), 256, 0, stream>>>(qkv, vtg);
  attn_kernel<<<512, 256, 0, stream>>>(qkv, vtg, bias, maddv, ctx);
  gemm_bt<512, 1><<<dim3(64, 4), 256, 0, stream>>>(ctx, woutT, (void*)out, 8192, 512);
}